// Round 11
// baseline (199.426 us; speedup 1.0000x reference)
//
#include <hip/hip_runtime.h>
#include <stdint.h>

typedef int i32x4 __attribute__((ext_vector_type(4)));

#define K_DIM 1024
#define BM 128
#define BN 128
#define BKK 64
#define NKT (K_DIM / BKK)   // 16

// Fragment-ordered int8 operand layout (producers aquant/wquant <-> consumer GEMM):
// fragment (F = row/16, T = k/64) is 1KB at offset ((F*16)+T)*1024; byte b
// (l=b>>4, j=b&15) holds value[row=F*16+(l&15)][k=T*64+(l>>4)*16+j].
// -> every fragment is ONE coalesced 1KB global_load_dwordx4 per wave (lane l -> +l*16).

// ---------------- helpers ----------------
__device__ __forceinline__ int quant1(float v, float inv) {
  float t = rintf(v * inv);                 // round half-to-even, matches jnp.round
  t = fminf(fmaxf(t, -128.0f), 127.0f);     // clip(-n-1, n)
  return (int)t;
}

#define SB __builtin_amdgcn_sched_barrier(0)
#define BAR __builtin_amdgcn_s_barrier()
#define WAIT_LGKM0 asm volatile("s_waitcnt lgkmcnt(0)" ::: "memory")

// ---------------- 1a) absmax partials ----------------
__global__ void absmax_part(const float* __restrict__ x, float* __restrict__ parts,
                            long long n4) {
  long long i = (long long)blockIdx.x * blockDim.x + threadIdx.x;
  const long long stride = (long long)gridDim.x * blockDim.x;
  const float4* x4 = (const float4*)x;
  float m = 0.0f;
  for (; i < n4; i += stride) {
    float4 v = x4[i];
    m = fmaxf(m, fmaxf(fmaxf(fabsf(v.x), fabsf(v.y)), fmaxf(fabsf(v.z), fabsf(v.w))));
  }
#pragma unroll
  for (int off = 32; off > 0; off >>= 1) m = fmaxf(m, __shfl_down(m, off, 64));
  __shared__ float sm[4];
  const int lane = threadIdx.x & 63, wid = threadIdx.x >> 6;
  if (lane == 0) sm[wid] = m;
  __syncthreads();
  if (threadIdx.x == 0)
    parts[blockIdx.x] = fmaxf(fmaxf(sm[0], sm[1]), fmaxf(sm[2], sm[3]));
}

// ---------------- 1b) absmax final reduce ----------------
__global__ void absmax_fin(const float* __restrict__ parts, unsigned int* __restrict__ amax_u,
                           int nparts) {
  const int t = threadIdx.x;
  float m = 0.0f;
  for (int i = t; i < nparts; i += 256) m = fmaxf(m, parts[i]);
#pragma unroll
  for (int off = 32; off > 0; off >>= 1) m = fmaxf(m, __shfl_down(m, off, 64));
  __shared__ float sm[4];
  const int lane = t & 63, wid = t >> 6;
  if (lane == 0) sm[wid] = m;
  __syncthreads();
  if (t == 0)
    amax_u[0] = __float_as_uint(fmaxf(fmaxf(sm[0], sm[1]), fmaxf(sm[2], sm[3])));
}

// ---------------- 2) per-channel weight quant + bias (frag-ordered wq) ----------------
__global__ void wquant_kernel(const float* __restrict__ w, const float* __restrict__ bias,
                              const unsigned int* __restrict__ amax_u,
                              signed char* __restrict__ wq,
                              float* __restrict__ bscale, float* __restrict__ bint) {
  const int o = blockIdx.x;
  const int t = threadIdx.x;          // handles k = 4t .. 4t+3
  float4 v = ((const float4*)(w + (size_t)o * K_DIM))[t];
  float m = fmaxf(fmaxf(fabsf(v.x), fabsf(v.y)), fmaxf(fabsf(v.z), fabsf(v.w)));
#pragma unroll
  for (int off = 32; off > 0; off >>= 1) m = fmaxf(m, __shfl_down(m, off, 64));
  __shared__ float sm[4];
  __shared__ float s_scale;
  const int lane = t & 63, wid = t >> 6;
  if (lane == 0) sm[wid] = m;
  __syncthreads();
  if (t == 0) {
    float wm = fmaxf(fmaxf(sm[0], sm[1]), fmaxf(sm[2], sm[3]));
    float wsc = fmaxf(wm, 1e-8f) / 127.0f;
    float asc = fmaxf(__uint_as_float(*amax_u), 1e-8f) / 127.0f;
    float bsc = wsc * asc;
    bscale[o] = bsc;
    bint[o] = rintf(bias[o] / bsc);
    s_scale = wsc;
  }
  __syncthreads();
  const float inv = 1.0f / s_scale;
  int q0 = quant1(v.x, inv), q1 = quant1(v.y, inv), q2 = quant1(v.z, inv), q3 = quant1(v.w, inv);
  unsigned int p = (unsigned)(q0 & 255) | ((unsigned)(q1 & 255) << 8) |
                   ((unsigned)(q2 & 255) << 16) | ((unsigned)(q3 & 255) << 24);
  const int F = o >> 4, T = t >> 4;
  const int l = (((t >> 2) & 3) << 4) | (o & 15);
  const int j = (t << 2) & 15;
  *(unsigned int*)(wq + (((size_t)F << 14) + (T << 10) + (l << 4) + j)) = p;
}

// ---------------- 3) activation quant: coalesced reads -> LDS frag image -> linear writes ----
__global__ __launch_bounds__(256) void aquant_kernel(
    const float* __restrict__ x, const unsigned int* __restrict__ amax_u,
    uint4* __restrict__ q16) {
  __shared__ unsigned int limg[4096];   // 16KB int8 frag image for this F
  const float asc = fmaxf(__uint_as_float(*amax_u), 1e-8f) / 127.0f;
  const float inv = 1.0f / asc;
  const int F = blockIdx.x;
  const int t = threadIdx.x;
  const int r = t >> 4, kq = t & 15;
  const float* rowp = x + (((size_t)F * 16 + r) << 10);
#pragma unroll
  for (int rep = 0; rep < 16; ++rep) {
    const int fi = rep * 16 + kq;           // float4 index in row, 0..255
    float4 v = ((const float4*)rowp)[fi];
    int q0 = quant1(v.x, inv), q1 = quant1(v.y, inv), q2 = quant1(v.z, inv), q3 = quant1(v.w, inv);
    unsigned int p = (unsigned)(q0 & 255) | ((unsigned)(q1 & 255) << 8) |
                     ((unsigned)(q2 & 255) << 16) | ((unsigned)(q3 & 255) << 24);
    const int k0 = fi << 2;
    const int T = k0 >> 6;
    const int l = (((k0 >> 4) & 3) << 4) | r;
    const int j = k0 & 15;
    limg[(T << 8) + (l << 2) + (j >> 2)] = p;
  }
  __syncthreads();
  const uint4* src = (const uint4*)limg;
#pragma unroll
  for (int rep2 = 0; rep2 < 4; ++rep2)
    q16[((size_t)F << 10) + rep2 * 256 + t] = src[rep2 * 256 + t];
}

// ---------------- 4) int8 GEMM: ALL-REGISTER K-loop (no LDS, no barriers) ----------------
// 128x128 tile, 4 waves (2x2), wave tile 64x64, acc[4][4] i32x4 (64 VGPR).
// Per K-tile per wave: 8 coalesced 1KB global b128 loads (4 A-frags + 4 B-frags,
// double-buffered reg sets) + 16 MFMA. Waves fully independent -> LDS pipe and
// matrix pipe finally overlap (the barrier-locked alternation capped all prior
// rounds at ~17% MfmaUtil). Operands are L2-resident via XCD swizzle.
__global__ __launch_bounds__(256, 3) void gemm_kernel(
    const signed char* __restrict__ A, const signed char* __restrict__ W,
    const float* __restrict__ bscale, const float* __restrict__ bint,
    float* __restrict__ out, int M, int N, int K) {
  __shared__ __align__(16) float Cst[64 * 128];   // 32KB, epilogue staging only

  // bijective XCD swizzle (gridDim.x % 8 == 0); 8 consecutive wgid share bm (A panel)
  const int nwg = gridDim.x;
  const int orig = blockIdx.x;
  const int wgid = (orig & 7) * (nwg >> 3) + (orig >> 3);
  const int nbn = N / BN;                 // 8
  const int bm = wgid / nbn;
  const int bn = wgid % nbn;
  const int m0 = bm * BM, n0 = bn * BN;

  const int tid = threadIdx.x;
  const int lane = tid & 63;
  const int wid = tid >> 6;          // 4 waves
  const int wr = wid >> 1;           // 2 wave-rows (64 rows each)
  const int wc = wid & 1;            // 2 wave-cols (64 cols each)

  // per-wave frag bases (frag F occupies 16KB; tile t at +t*1KB; lane at +l*16)
  const signed char* gA = A + (((size_t)(m0 >> 4) + wr * 4) << 14) + (lane << 4);
  const signed char* gB = W + (((size_t)(n0 >> 4) + wc * 4) << 14) + (lane << 4);

  i32x4 acc[4][4];
#pragma unroll
  for (int i = 0; i < 4; i++)
#pragma unroll
    for (int j = 0; j < 4; j++) acc[i][j] = (i32x4){0, 0, 0, 0};

  i32x4 aA[4], aB[4], bA[4], bB[4];

#define LDSET(AR, BR, tt)                                                      \
  do {                                                                         \
    AR[0] = *(const i32x4*)(gA + ((size_t)0 << 14) + ((tt) << 10));            \
    AR[1] = *(const i32x4*)(gA + ((size_t)1 << 14) + ((tt) << 10));            \
    AR[2] = *(const i32x4*)(gA + ((size_t)2 << 14) + ((tt) << 10));            \
    AR[3] = *(const i32x4*)(gA + ((size_t)3 << 14) + ((tt) << 10));            \
    BR[0] = *(const i32x4*)(gB + ((size_t)0 << 14) + ((tt) << 10));            \
    BR[1] = *(const i32x4*)(gB + ((size_t)1 << 14) + ((tt) << 10));            \
    BR[2] = *(const i32x4*)(gB + ((size_t)2 << 14) + ((tt) << 10));            \
    BR[3] = *(const i32x4*)(gB + ((size_t)3 << 14) + ((tt) << 10));            \
  } while (0)

#define MFMA16(AR, BR)                                                         \
  do {                                                                         \
    __builtin_amdgcn_s_setprio(1);                                             \
    _Pragma("unroll") for (int i_ = 0; i_ < 4; i_++)                           \
      _Pragma("unroll") for (int j_ = 0; j_ < 4; j_++)                         \
        acc[i_][j_] = __builtin_amdgcn_mfma_i32_16x16x64_i8(                   \
            AR[i_], BR[j_], acc[i_][j_], 0, 0, 0);                             \
    __builtin_amdgcn_s_setprio(0);                                             \
  } while (0)

  // fully unrolled, reg-double-buffered: load(t+1) issued before MFMA(t);
  // compiler inserts counted per-register vmcnt waits (never a full drain).
  LDSET(aA, bA, 0);
  LDSET(aB, bB, 1);  MFMA16(aA, bA);    // t=0
  LDSET(aA, bA, 2);  MFMA16(aB, bB);    // t=1
  LDSET(aB, bB, 3);  MFMA16(aA, bA);    // t=2
  LDSET(aA, bA, 4);  MFMA16(aB, bB);    // t=3
  LDSET(aB, bB, 5);  MFMA16(aA, bA);    // t=4
  LDSET(aA, bA, 6);  MFMA16(aB, bB);    // t=5
  LDSET(aB, bB, 7);  MFMA16(aA, bA);    // t=6
  LDSET(aA, bA, 8);  MFMA16(aB, bB);    // t=7
  LDSET(aB, bB, 9);  MFMA16(aA, bA);    // t=8
  LDSET(aA, bA, 10); MFMA16(aB, bB);    // t=9
  LDSET(aB, bB, 11); MFMA16(aA, bA);    // t=10
  LDSET(aA, bA, 12); MFMA16(aB, bB);    // t=11
  LDSET(aB, bB, 13); MFMA16(aA, bA);    // t=12
  LDSET(aA, bA, 14); MFMA16(aB, bB);    // t=13
  LDSET(aB, bB, 15); MFMA16(aA, bA);    // t=14
  MFMA16(aB, bB);                       // t=15

#undef MFMA16
#undef LDSET

  // ---- epilogue: LDS-staged coalesced C writes, 2 halves of 64 rows ----
  const int rr = (lane >> 4) * 4;
  const int cc = lane & 15;
#pragma unroll
  for (int h = 0; h < 2; ++h) {
    if (h == 1) BAR;                    // writers of h=1 wait for h=0 reads
    if (wr == h) {
#pragma unroll
      for (int j = 0; j < 4; j++) {
        const int colL = wc * 64 + j * 16 + cc;
        const float bs = bscale[n0 + colL];
        const float bi = bint[n0 + colL];
#pragma unroll
        for (int i = 0; i < 4; i++)
#pragma unroll
          for (int r = 0; r < 4; r++)
            Cst[(i * 16 + rr + r) * 128 + colL] = ((float)acc[i][j][r] + bi) * bs;
      }
    }
    WAIT_LGKM0;
    BAR;                                // writes visible to all waves
    const size_t rowbase = (size_t)(m0 + h * 64) * N + n0;
#pragma unroll
    for (int it = 0; it < 8; ++it) {
      const int r_ = it * 8 + wid * 2 + (lane >> 5);   // 0..63
      const int c_ = (lane & 31) * 4;
      float4 v = *(const float4*)&Cst[r_ * 128 + c_];
      *(float4*)&out[rowbase + (size_t)r_ * N + c_] = v;
    }
    WAIT_LGKM0;                         // reads done before h=1 overwrite
  }
}

// ---------------- launch ----------------
extern "C" void kernel_launch(void* const* d_in, const int* in_sizes, int n_in,
                              void* d_out, int out_size, void* d_ws, size_t ws_size,
                              hipStream_t stream) {
  const float* hs = (const float*)d_in[0];
  const float* w = (const float*)d_in[1];
  const float* bias = (const float*)d_in[2];
  float* out = (float*)d_out;

  const long long n = (long long)in_sizes[0];     // 50331648
  const int K = K_DIM;                            // 1024
  const int O = in_sizes[2];                      // 1024
  const int M = (int)(n / K);                     // 49152

  // workspace layout
  char* ws = (char*)d_ws;
  unsigned int* amax_u = (unsigned int*)ws;                        // 4 B
  float* parts = (float*)(ws + 1024);                              // 8 KB
  float* bscale = (float*)(ws + 16384);                            // 4 KB
  float* bint = (float*)(ws + 20480);                              // 4 KB
  signed char* wq = (signed char*)(ws + 65536);                    // 1 MB (frag-ordered)
  signed char* xq = (signed char*)(ws + 65536 + 1048576);          // 48 MB (frag-ordered)

  const long long n4 = n / 4;
  absmax_part<<<2048, 256, 0, stream>>>(hs, parts, n4);
  absmax_fin<<<1, 256, 0, stream>>>(parts, amax_u, 2048);
  wquant_kernel<<<O, 256, 0, stream>>>(w, bias, amax_u, wq, bscale, bint);
  aquant_kernel<<<M / 16, 256, 0, stream>>>(hs, amax_u, (uint4*)xq);   // 3072 blocks

  const int nblocks = (M / BM) * (O / BN);        // 384 * 8 = 3072
  gemm_kernel<<<nblocks, 256, 0, stream>>>(xq, wq, bscale, bint, out, M, O, K);
}

// Round 12
// 187.135 us; speedup vs baseline: 1.0657x; 1.0657x over previous
//
#include <hip/hip_runtime.h>
#include <stdint.h>

typedef int i32x4 __attribute__((ext_vector_type(4)));
typedef int i32x16 __attribute__((ext_vector_type(16)));

#define K_DIM 1024
#define BM 256
#define BN 256
#define BKK 64
#define NKT (K_DIM / BKK)   // 16

// 32-row fragment-ordered int8 layout (producers <-> GEMM):
// fragment (F = row/32, T = k/32) is 1KB at offset (F*32 + T)*1024; byte
// (l = b>>4, j = b&15) holds value[row = F*32 + (l&31)][k = T*32 + (l>>5)*16 + j].
// Matches mfma_i32_32x32x32_i8 A/B lane mapping (row|col = l&31, k = (l>>5)*16+j).
// -> every fragment is ONE coalesced 1KB load (gld_lds for A, b128-to-reg for B).

// ---------------- helpers ----------------
__device__ __forceinline__ int quant1(float v, float inv) {
  float t = rintf(v * inv);                 // round half-to-even, matches jnp.round
  t = fminf(fmaxf(t, -128.0f), 127.0f);     // clip(-n-1, n)
  return (int)t;
}

__device__ __forceinline__ void gld_lds16(const signed char* g, signed char* l) {
  typedef const __attribute__((address_space(1))) unsigned int* gp_t;
  typedef __attribute__((address_space(3))) unsigned int* lp_t;
  __builtin_amdgcn_global_load_lds((gp_t)(const void*)g, (lp_t)(void*)l, 16, 0, 0);
}

#define SB __builtin_amdgcn_sched_barrier(0)
#define BAR __builtin_amdgcn_s_barrier()

// ---------------- 1a) absmax partials ----------------
__global__ void absmax_part(const float* __restrict__ x, float* __restrict__ parts,
                            long long n4) {
  long long i = (long long)blockIdx.x * blockDim.x + threadIdx.x;
  const long long stride = (long long)gridDim.x * blockDim.x;
  const float4* x4 = (const float4*)x;
  float m = 0.0f;
  for (; i < n4; i += stride) {
    float4 v = x4[i];
    m = fmaxf(m, fmaxf(fmaxf(fabsf(v.x), fabsf(v.y)), fmaxf(fabsf(v.z), fabsf(v.w))));
  }
#pragma unroll
  for (int off = 32; off > 0; off >>= 1) m = fmaxf(m, __shfl_down(m, off, 64));
  __shared__ float sm[4];
  const int lane = threadIdx.x & 63, wid = threadIdx.x >> 6;
  if (lane == 0) sm[wid] = m;
  __syncthreads();
  if (threadIdx.x == 0)
    parts[blockIdx.x] = fmaxf(fmaxf(sm[0], sm[1]), fmaxf(sm[2], sm[3]));
}

// ---------------- 1b) absmax final reduce ----------------
__global__ void absmax_fin(const float* __restrict__ parts, unsigned int* __restrict__ amax_u,
                           int nparts) {
  const int t = threadIdx.x;
  float m = 0.0f;
  for (int i = t; i < nparts; i += 256) m = fmaxf(m, parts[i]);
#pragma unroll
  for (int off = 32; off > 0; off >>= 1) m = fmaxf(m, __shfl_down(m, off, 64));
  __shared__ float sm[4];
  const int lane = t & 63, wid = t >> 6;
  if (lane == 0) sm[wid] = m;
  __syncthreads();
  if (t == 0)
    amax_u[0] = __float_as_uint(fmaxf(fmaxf(sm[0], sm[1]), fmaxf(sm[2], sm[3])));
}

// ---------------- 2) per-channel weight quant + bias (32-frag wq) ----------------
__global__ void wquant_kernel(const float* __restrict__ w, const float* __restrict__ bias,
                              const unsigned int* __restrict__ amax_u,
                              signed char* __restrict__ wq,
                              float* __restrict__ bscale, float* __restrict__ bint) {
  const int o = blockIdx.x;
  const int t = threadIdx.x;          // handles k = 4t .. 4t+3
  float4 v = ((const float4*)(w + (size_t)o * K_DIM))[t];
  float m = fmaxf(fmaxf(fabsf(v.x), fabsf(v.y)), fmaxf(fabsf(v.z), fabsf(v.w)));
#pragma unroll
  for (int off = 32; off > 0; off >>= 1) m = fmaxf(m, __shfl_down(m, off, 64));
  __shared__ float sm[4];
  __shared__ float s_scale;
  const int lane = t & 63, wid = t >> 6;
  if (lane == 0) sm[wid] = m;
  __syncthreads();
  if (t == 0) {
    float wm = fmaxf(fmaxf(sm[0], sm[1]), fmaxf(sm[2], sm[3]));
    float wsc = fmaxf(wm, 1e-8f) / 127.0f;
    float asc = fmaxf(__uint_as_float(*amax_u), 1e-8f) / 127.0f;
    float bsc = wsc * asc;
    bscale[o] = bsc;
    bint[o] = rintf(bias[o] / bsc);
    s_scale = wsc;
  }
  __syncthreads();
  const float inv = 1.0f / s_scale;
  int q0 = quant1(v.x, inv), q1 = quant1(v.y, inv), q2 = quant1(v.z, inv), q3 = quant1(v.w, inv);
  unsigned int p = (unsigned)(q0 & 255) | ((unsigned)(q1 & 255) << 8) |
                   ((unsigned)(q2 & 255) << 16) | ((unsigned)(q3 & 255) << 24);
  // 32-frag dest: F=o>>5, T=t>>3, hi=(t>>2)&1, l=(o&31)|(hi<<5), j=(t<<2)&15
  const int F = o >> 5, T = t >> 3;
  const int l = (o & 31) | (((t >> 2) & 1) << 5);
  const int j = (t << 2) & 15;
  *(unsigned int*)(wq + (((size_t)(F * 32 + T)) << 10) + (l << 4) + j) = p;
}

// ---------------- 3) activation quant: coalesced reads -> LDS frag image -> 256B-run writes ----
// Block b covers rows 16b..16b+15 (half of 32-row frag group F32=b>>1, half bh=b&1).
__global__ __launch_bounds__(256) void aquant_kernel(
    const float* __restrict__ x, const unsigned int* __restrict__ amax_u,
    uint4* __restrict__ q16) {
  __shared__ unsigned int limg[4096];   // [T32:32][hi:2][r:16][4 uints] = 16KB
  const float asc = fmaxf(__uint_as_float(*amax_u), 1e-8f) / 127.0f;
  const float inv = 1.0f / asc;
  const int b = blockIdx.x;
  const int F32 = b >> 1, bh = b & 1;
  const int t = threadIdx.x;
  const int r = t >> 4, kq = t & 15;
  const float* rowp = x + (((size_t)b * 16 + r) << 10);
#pragma unroll
  for (int rep = 0; rep < 16; ++rep) {
    const int fi = rep * 16 + kq;           // float4 index in row, 0..255
    float4 v = ((const float4*)rowp)[fi];
    int q0 = quant1(v.x, inv), q1 = quant1(v.y, inv), q2 = quant1(v.z, inv), q3 = quant1(v.w, inv);
    unsigned int p = (unsigned)(q0 & 255) | ((unsigned)(q1 & 255) << 8) |
                     ((unsigned)(q2 & 255) << 16) | ((unsigned)(q3 & 255) << 24);
    const int k0 = fi << 2;
    const int T32 = k0 >> 5;
    const int hi = (k0 >> 4) & 1;
    const int j = k0 & 15;
    limg[(((T32 << 1) | hi) << 6) + (r << 2) + (j >> 2)] = p;
  }
  __syncthreads();
  const uint4* src = (const uint4*)limg;
#pragma unroll
  for (int rep2 = 0; rep2 < 4; ++rep2) {
    const int e = rep2 * 256 + t;           // 0..1023 = (T32*2+hs)*16 + r
    const int T32 = e >> 5, hs = (e >> 4) & 1, rr = e & 15;
    q16[(((size_t)(F32 * 32 + T32)) << 6) + (hs * 32 + bh * 16 + rr)] = src[e];
  }
}

// ---------------- 4) int8 GEMM: 32x32x32 MFMA, A via LDS, B->regs, direct line epilogue ----
// 256x256 tile, 512 thr = 8 waves (2x4), wave tile 128x64.
// acc[4][2] i32x16 (128 VGPR). Per K-tile/wave: 2 gld_lds (A), 4 b128 global (B),
// 8 ds_read_b128 (A frags), 16 MFMA, counted vmcnt(8), ONE barrier.
// Epilogue: DIRECT stores — each reg's 32-lane half writes one full 128B line;
// no LDS, no barrier -> stores drain while next block-round computes.
__global__ __launch_bounds__(512, 2) void gemm_kernel(
    const signed char* __restrict__ A, const signed char* __restrict__ W,
    const float* __restrict__ bscale, const float* __restrict__ bint,
    float* __restrict__ out, int M, int N, int K) {
  extern __shared__ __align__(16) signed char smem[];   // 65536: 4 bufs x 16 frags x 1KB
  signed char* Abase = smem;

  // bijective XCD swizzle (gridDim.x % 8 == 0)
  const int nwg = gridDim.x;
  const int orig = blockIdx.x;
  const int wgid = (orig & 7) * (nwg >> 3) + (orig >> 3);
  const int nbn = N / BN;                 // 4
  const int bm = wgid / nbn;
  const int bn = wgid % nbn;
  const int m0 = bm * BM, n0 = bn * BN;

  const int tid = threadIdx.x;
  const int lane = tid & 63;
  const int wid = tid >> 6;          // 8 waves
  const int wr = wid >> 2;           // 2 wave-rows (128 rows)
  const int wc = wid & 3;            // 4 wave-cols (64 cols)

  // A: wave stages frags f=wid, wid+8; f <-> (F32l=f>>1, kk=f&1)
  const signed char* gaf =
      A + (((size_t)((m0 >> 5) + (wid >> 1)) * 32 + (wid & 1)) << 10) + (lane << 4);
  const size_t fs8 = (size_t)128 << 10;   // f -> f+8 : +4 F32 groups
  // B: wave's 2 col-groups (wc*2+g); frag (g, tile t, kk) at g*32KB + (2t+kk)*1KB
  const signed char* gbf =
      W + (((size_t)((n0 >> 5) + wc * 2) * 32) << 10) + (lane << 4);

  i32x16 acc[4][2];
#pragma unroll
  for (int i = 0; i < 4; i++)
#pragma unroll
    for (int j = 0; j < 2; j++)
#pragma unroll
      for (int r = 0; r < 16; r++) acc[i][j][r] = 0;

  i32x4 af[4][2];
  i32x4 bA[2][2], bB[2][2];

#define LOADB(L, tt)                                                           \
  do {                                                                         \
    L[0][0] = *(const i32x4*)(gbf + (((size_t)(tt) * 2 + 0) << 10));           \
    L[0][1] = *(const i32x4*)(gbf + (((size_t)(tt) * 2 + 1) << 10));           \
    L[1][0] = *(const i32x4*)(gbf + ((size_t)1 << 15) + (((size_t)(tt) * 2 + 0) << 10)); \
    L[1][1] = *(const i32x4*)(gbf + ((size_t)1 << 15) + (((size_t)(tt) * 2 + 1) << 10)); \
  } while (0)

#define ISSUEA(tt)                                                             \
  do {                                                                         \
    gld_lds16(gaf + ((size_t)(tt) << 11),                                      \
              Abase + ((((tt) & 3) * 16 + wid) << 10));                        \
    gld_lds16(gaf + fs8 + ((size_t)(tt) << 11),                                \
              Abase + ((((tt) & 3) * 16 + wid + 8) << 10));                    \
  } while (0)

#define RD_A(t)                                                                \
  do {                                                                         \
    _Pragma("unroll") for (int m_ = 0; m_ < 4; m_++)                           \
      _Pragma("unroll") for (int k_ = 0; k_ < 2; k_++)                         \
        af[m_][k_] = *(const i32x4*)(Abase + ((((t) & 3) * 16 +                \
                        (wr * 4 + m_) * 2 + k_) << 10) + (lane << 4));         \
  } while (0)

#define MFMA16(U)                                                              \
  do {                                                                         \
    __builtin_amdgcn_s_setprio(1);                                             \
    _Pragma("unroll") for (int m_ = 0; m_ < 4; m_++)                           \
      _Pragma("unroll") for (int g_ = 0; g_ < 2; g_++)                         \
        _Pragma("unroll") for (int k_ = 0; k_ < 2; k_++)                       \
          acc[m_][g_] = __builtin_amdgcn_mfma_i32_32x32x32_i8(                 \
              af[m_][k_], U[g_][k_], acc[m_][g_], 0, 0, 0);                    \
    __builtin_amdgcn_s_setprio(0);                                             \
  } while (0)

#define TILE(t, U, L, DOB, DOA, VMW, DOVM)                                     \
  do {                                                                         \
    if (DOB) LOADB(L, (t) + 1);                                                \
    if (DOA) ISSUEA((t) + 3);                                                  \
    SB;                                                                        \
    RD_A(t);                                                                   \
    MFMA16(U);                                                                 \
    if (DOVM) { asm volatile("s_waitcnt " VMW ::: "memory"); }                 \
    SB; BAR; SB;                                                               \
  } while (0)

  // prologue: A(0..2) staged (6 loads), B(0) (4 loads); vmcnt(8) lands A(0).
  ISSUEA(0); ISSUEA(1); ISSUEA(2);
  LOADB(bA, 0);
  asm volatile("s_waitcnt vmcnt(8)" ::: "memory");
  SB; BAR; SB;

  TILE(0,  bA, bB, 1, 1, "vmcnt(8)", 1);
  TILE(1,  bB, bA, 1, 1, "vmcnt(8)", 1);
  TILE(2,  bA, bB, 1, 1, "vmcnt(8)", 1);
  TILE(3,  bB, bA, 1, 1, "vmcnt(8)", 1);
  TILE(4,  bA, bB, 1, 1, "vmcnt(8)", 1);
  TILE(5,  bB, bA, 1, 1, "vmcnt(8)", 1);
  TILE(6,  bA, bB, 1, 1, "vmcnt(8)", 1);
  TILE(7,  bB, bA, 1, 1, "vmcnt(8)", 1);
  TILE(8,  bA, bB, 1, 1, "vmcnt(8)", 1);
  TILE(9,  bB, bA, 1, 1, "vmcnt(8)", 1);
  TILE(10, bA, bB, 1, 1, "vmcnt(8)", 1);
  TILE(11, bB, bA, 1, 1, "vmcnt(8)", 1);
  TILE(12, bA, bB, 1, 1, "vmcnt(8)", 1);
  TILE(13, bB, bA, 1, 0, "vmcnt(6)", 1);   // last A (A15) issued at t=12
  TILE(14, bA, bB, 1, 0, "vmcnt(4)", 1);   // forces A15 landed (FIFO)
  TILE(15, bB, bA, 0, 0, "", 0);

#undef TILE
#undef MFMA16
#undef RD_A
#undef ISSUEA
#undef LOADB

  // ---- epilogue: DIRECT full-line stores from 32x32 C/D layout ----
  // col = lane&31 (32 consecutive -> one 128B line per half-wave per reg);
  // row = base + (reg&3) + 8*(reg>>2) + 4*(lane>>5). No LDS, no barriers.
  const int cl = lane & 31;
  const int hi4 = (lane >> 5) << 2;
#pragma unroll
  for (int g = 0; g < 2; g++) {
    const int col = n0 + (wc * 2 + g) * 32 + cl;
    const float bs = bscale[col];
    const float bi = bint[col];
#pragma unroll
    for (int m = 0; m < 4; m++) {
      const int rowb = m0 + (wr * 4 + m) * 32 + hi4;
#pragma unroll
      for (int r = 0; r < 16; r++) {
        const int row = rowb + (r & 3) + ((r >> 2) << 3);
        out[(size_t)row * N + col] = ((float)acc[m][g][r] + bi) * bs;
      }
    }
  }
}

// ---------------- launch ----------------
extern "C" void kernel_launch(void* const* d_in, const int* in_sizes, int n_in,
                              void* d_out, int out_size, void* d_ws, size_t ws_size,
                              hipStream_t stream) {
  const float* hs = (const float*)d_in[0];
  const float* w = (const float*)d_in[1];
  const float* bias = (const float*)d_in[2];
  float* out = (float*)d_out;

  const long long n = (long long)in_sizes[0];     // 50331648
  const int K = K_DIM;                            // 1024
  const int O = in_sizes[2];                      // 1024
  const int M = (int)(n / K);                     // 49152

  // workspace layout
  char* ws = (char*)d_ws;
  unsigned int* amax_u = (unsigned int*)ws;                        // 4 B
  float* parts = (float*)(ws + 1024);                              // 8 KB
  float* bscale = (float*)(ws + 16384);                            // 4 KB
  float* bint = (float*)(ws + 20480);                              // 4 KB
  signed char* wq = (signed char*)(ws + 65536);                    // 1 MB (32-frag)
  signed char* xq = (signed char*)(ws + 65536 + 1048576);          // 48 MB (32-frag)

  hipFuncSetAttribute((const void*)gemm_kernel,
                      hipFuncAttributeMaxDynamicSharedMemorySize, 65536);

  const long long n4 = n / 4;
  absmax_part<<<2048, 256, 0, stream>>>(hs, parts, n4);
  absmax_fin<<<1, 256, 0, stream>>>(parts, amax_u, 2048);
  wquant_kernel<<<O, 256, 0, stream>>>(w, bias, amax_u, wq, bscale, bint);
  aquant_kernel<<<M / 16, 256, 0, stream>>>(hs, amax_u, (uint4*)xq);   // 3072 blocks

  const int nblocks = (M / BM) * (O / BN);        // 192 * 4 = 768
  gemm_kernel<<<nblocks, 512, 65536, stream>>>(xq, wq, bscale, bint, out, M, O, K);
}